// Round 1
// baseline (756.735 us; speedup 1.0000x reference)
//
#include <hip/hip_runtime.h>

// ---------------- problem constants ----------------
#define NNODES 100000

// ---------------- workspace layout (bytes) ----------------
// all offsets 128B-aligned
#define OFF_CNT      0UL            // int[100000]
#define OFF_ROWPTR   400128UL       // int[100001]
#define OFF_CURSOR   800384UL       // int[100000]
#define OFF_DINV     1200640UL      // float[100000]
#define OFF_PART     1600896UL      // int[128]
#define OFF_PO       1603072UL      // int[128]
#define OFF_COL      1605632UL      // int[1600000]  -> ends 8005632
#define OFF_H1G      8005632UL      // float[100000*128] = 51.2MB -> ends 59205632
#define OFF_H1OUT    59205632UL     // float[100000*128] -> ends 110405632
// h2g reuses OFF_H1G (h1g dead after agg1)

// ---------------- degree count ----------------
__global__ __launch_bounds__(256) void count_kernel(const int* __restrict__ dst,
                                                    int* __restrict__ cnt, int E) {
    int i = blockIdx.x * 256 + threadIdx.x;
    if (i < E) atomicAdd(&cnt[dst[i]], 1);
}

// ---------------- prefix scan (3 phases) ----------------
__global__ __launch_bounds__(256) void scan_a(const int* __restrict__ cnt,
                                              int* __restrict__ partials, int n) {
    __shared__ int sdata[256];
    int t = threadIdx.x;
    int base = blockIdx.x * 1024 + t * 4;
    int s = 0;
#pragma unroll
    for (int i = 0; i < 4; ++i) {
        int idx = base + i;
        if (idx < n) s += cnt[idx];
    }
    sdata[t] = s;
    __syncthreads();
    for (int off = 128; off > 0; off >>= 1) {
        if (t < off) sdata[t] += sdata[t + off];
        __syncthreads();
    }
    if (t == 0) partials[blockIdx.x] = sdata[0];
}

__global__ __launch_bounds__(128) void scan_b(const int* __restrict__ partials,
                                              int* __restrict__ po,
                                              int* __restrict__ rowptr,
                                              int nblocks, int n) {
    __shared__ int s[128];
    int t = threadIdx.x;  // 128 threads
    int v = (t < nblocks) ? partials[t] : 0;
    s[t] = v;
    __syncthreads();
    for (int off = 1; off < 128; off <<= 1) {
        int add = (t >= off) ? s[t - off] : 0;
        __syncthreads();
        s[t] += add;
        __syncthreads();
    }
    if (t < nblocks) po[t] = s[t] - v;  // exclusive
    if (t == 127) rowptr[n] = s[127];   // total = E
}

__global__ __launch_bounds__(256) void scan_c(const int* __restrict__ cnt,
                                              const int* __restrict__ po,
                                              int* __restrict__ rowptr,
                                              int* __restrict__ cursor,
                                              float* __restrict__ dinv, int n) {
    __shared__ int sdata[256];
    int t = threadIdx.x;
    int base = blockIdx.x * 1024 + t * 4;
    int v[4];
    int s = 0;
#pragma unroll
    for (int i = 0; i < 4; ++i) {
        int idx = base + i;
        v[i] = (idx < n) ? cnt[idx] : 0;
        s += v[i];
    }
    sdata[t] = s;
    __syncthreads();
    int own = s;
    for (int off = 1; off < 256; off <<= 1) {
        int add = (t >= off) ? sdata[t - off] : 0;
        __syncthreads();
        sdata[t] += add;
        __syncthreads();
    }
    int offset = po[blockIdx.x] + sdata[t] - own;
#pragma unroll
    for (int i = 0; i < 4; ++i) {
        int idx = base + i;
        if (idx < n) {
            rowptr[idx] = offset;
            cursor[idx] = offset;
            dinv[idx] = rsqrtf((float)(v[i] + 1));  // +1 self-loop
            offset += v[i];
        }
    }
}

__global__ __launch_bounds__(256) void fill_kernel(const int* __restrict__ src,
                                                   const int* __restrict__ dst,
                                                   int* __restrict__ cursor,
                                                   int* __restrict__ colarr, int E) {
    int i = blockIdx.x * 256 + threadIdx.x;
    if (i < E) {
        int d = dst[i];
        int slot = atomicAdd(&cursor[d], 1);
        colarr[slot] = src[i];
    }
}

// ---------------- fp32 tiled GEMM, epilogue scales row by dinv[row] ----------------
// C[m][n] = (sum_k A[m][k] * W[k][n]) * dinv[m]      A:[M,K]  W:[K,BN]  C:[M,BN]
template <int BM, int BN, int TM, int TN, int KC>
__global__ __launch_bounds__(256) void gemm_scale(const float* __restrict__ A,
                                                  const float* __restrict__ W,
                                                  const float* __restrict__ dinv,
                                                  float* __restrict__ C,
                                                  int M, int K) {
    static_assert(TN == 4, "TN must be 4 (float4 path)");
    constexpr int NT = BN / TN;              // threads along N
    constexpr int LDA = KC + 4;              // pad for banks, keep 16B align
    __shared__ float As[BM][LDA];
    __shared__ float Ws[KC][BN];

    int tid = threadIdx.x;
    int tx = tid % NT;
    int ty = tid / NT;
    int m0 = blockIdx.x * BM;

    float acc[TM][TN];
#pragma unroll
    for (int i = 0; i < TM; ++i)
#pragma unroll
        for (int j = 0; j < TN; ++j) acc[i][j] = 0.f;

    for (int k0 = 0; k0 < K; k0 += KC) {
        // stage A tile: BM x KC
        constexpr int AV = BM * KC / 4 / 256;
#pragma unroll
        for (int i = 0; i < AV; ++i) {
            int v = tid + i * 256;
            int row = v / (KC / 4);
            int kk = (v % (KC / 4)) * 4;
            int gr = m0 + row;
            float4 val = make_float4(0.f, 0.f, 0.f, 0.f);
            if (gr < M) val = *(const float4*)&A[(size_t)gr * K + k0 + kk];
            *(float4*)&As[row][kk] = val;
        }
        // stage W tile: KC x BN
        constexpr int WV = KC * BN / 4 / 256;
#pragma unroll
        for (int i = 0; i < WV; ++i) {
            int v = tid + i * 256;
            int kr = v / (BN / 4);
            int c4 = (v % (BN / 4)) * 4;
            *(float4*)&Ws[kr][c4] = *(const float4*)&W[(size_t)(k0 + kr) * BN + c4];
        }
        __syncthreads();

#pragma unroll
        for (int kc = 0; kc < KC; kc += 4) {
            float4 av[TM];
#pragma unroll
            for (int i = 0; i < TM; ++i) av[i] = *(const float4*)&As[ty * TM + i][kc];
            float4 bv[4];
#pragma unroll
            for (int q = 0; q < 4; ++q) bv[q] = *(const float4*)&Ws[kc + q][tx * TN];
#pragma unroll
            for (int i = 0; i < TM; ++i) {
                acc[i][0] += av[i].x * bv[0].x + av[i].y * bv[1].x + av[i].z * bv[2].x + av[i].w * bv[3].x;
                acc[i][1] += av[i].x * bv[0].y + av[i].y * bv[1].y + av[i].z * bv[2].y + av[i].w * bv[3].y;
                acc[i][2] += av[i].x * bv[0].z + av[i].y * bv[1].z + av[i].z * bv[2].z + av[i].w * bv[3].z;
                acc[i][3] += av[i].x * bv[0].w + av[i].y * bv[1].w + av[i].z * bv[2].w + av[i].w * bv[3].w;
            }
        }
        __syncthreads();
    }

#pragma unroll
    for (int i = 0; i < TM; ++i) {
        int r = m0 + ty * TM + i;
        if (r < M) {
            float dv = dinv[r];
            float4 o;
            o.x = acc[i][0] * dv;
            o.y = acc[i][1] * dv;
            o.z = acc[i][2] * dv;
            o.w = acc[i][3] * dv;
            *(float4*)&C[(size_t)r * BN + tx * TN] = o;
        }
    }
}

// ---------------- aggregation: out[n] = relu(dinv[n]*(sum_nbr g[src] + g[n]) + b) ----------------
// 128 channels: one wave per node, float2 per lane
__global__ __launch_bounds__(256) void agg_f2(const float2* __restrict__ g,
                                              const int* __restrict__ rowptr,
                                              const int* __restrict__ colarr,
                                              const float* __restrict__ dinv,
                                              const float* __restrict__ bias,
                                              float2* __restrict__ out, int n) {
    int node = blockIdx.x * 4 + (threadIdx.x >> 6);
    int lane = threadIdx.x & 63;
    if (node >= n) return;
    int beg = rowptr[node];
    int end = rowptr[node + 1];
    float2 acc = g[(size_t)node * 64 + lane];  // self loop
    int p = beg;
    for (; p + 4 <= end; p += 4) {
        int s0 = colarr[p], s1 = colarr[p + 1], s2 = colarr[p + 2], s3 = colarr[p + 3];
        float2 v0 = g[(size_t)s0 * 64 + lane];
        float2 v1 = g[(size_t)s1 * 64 + lane];
        float2 v2 = g[(size_t)s2 * 64 + lane];
        float2 v3 = g[(size_t)s3 * 64 + lane];
        acc.x += (v0.x + v1.x) + (v2.x + v3.x);
        acc.y += (v0.y + v1.y) + (v2.y + v3.y);
    }
    for (; p < end; ++p) {
        float2 v = g[(size_t)colarr[p] * 64 + lane];
        acc.x += v.x;
        acc.y += v.y;
    }
    float dv = dinv[node];
    float2 b = ((const float2*)bias)[lane];
    float2 o;
    o.x = fmaxf(fmaf(acc.x, dv, b.x), 0.f);
    o.y = fmaxf(fmaf(acc.y, dv, b.y), 0.f);
    out[(size_t)node * 64 + lane] = o;
}

// 64 channels: one wave per node, float per lane
__global__ __launch_bounds__(256) void agg_f1(const float* __restrict__ g,
                                              const int* __restrict__ rowptr,
                                              const int* __restrict__ colarr,
                                              const float* __restrict__ dinv,
                                              const float* __restrict__ bias,
                                              float* __restrict__ out, int n) {
    int node = blockIdx.x * 4 + (threadIdx.x >> 6);
    int lane = threadIdx.x & 63;
    if (node >= n) return;
    int beg = rowptr[node];
    int end = rowptr[node + 1];
    float acc = g[(size_t)node * 64 + lane];  // self loop
    int p = beg;
    for (; p + 4 <= end; p += 4) {
        int s0 = colarr[p], s1 = colarr[p + 1], s2 = colarr[p + 2], s3 = colarr[p + 3];
        float v0 = g[(size_t)s0 * 64 + lane];
        float v1 = g[(size_t)s1 * 64 + lane];
        float v2 = g[(size_t)s2 * 64 + lane];
        float v3 = g[(size_t)s3 * 64 + lane];
        acc += (v0 + v1) + (v2 + v3);
    }
    for (; p < end; ++p) acc += g[(size_t)colarr[p] * 64 + lane];
    float dv = dinv[node];
    float o = fmaxf(fmaf(acc, dv, bias[lane]), 0.f);
    out[(size_t)node * 64 + lane] = o;
}

extern "C" void kernel_launch(void* const* d_in, const int* in_sizes, int n_in,
                              void* d_out, int out_size, void* d_ws, size_t ws_size,
                              hipStream_t stream) {
    const float* x  = (const float*)d_in[0];
    const int*   ei = (const int*)d_in[1];
    const float* W1 = (const float*)d_in[2];
    const float* b1 = (const float*)d_in[3];
    const float* W2 = (const float*)d_in[4];
    const float* b2 = (const float*)d_in[5];
    float* out = (float*)d_out;

    const int E = in_sizes[1] / 2;
    const int H1 = in_sizes[3];                 // 128
    const int K1 = in_sizes[2] / H1;            // 256
    const int N = in_sizes[0] / K1;             // 100000
    const int* src = ei;
    const int* dst = ei + E;

    char* ws = (char*)d_ws;
    int*   cnt      = (int*)(ws + OFF_CNT);
    int*   rowptr   = (int*)(ws + OFF_ROWPTR);
    int*   cursor   = (int*)(ws + OFF_CURSOR);
    float* dinv     = (float*)(ws + OFF_DINV);
    int*   partials = (int*)(ws + OFF_PART);
    int*   po       = (int*)(ws + OFF_PO);
    int*   colarr   = (int*)(ws + OFF_COL);
    float* h1g      = (float*)(ws + OFF_H1G);
    float* h1out    = (float*)(ws + OFF_H1OUT);
    float* h2g      = (float*)(ws + OFF_H1G);   // reuse

    hipMemsetAsync(cnt, 0, (size_t)N * sizeof(int), stream);
    count_kernel<<<(E + 255) / 256, 256, 0, stream>>>(dst, cnt, E);

    int nsblk = (N + 1023) / 1024;  // 98
    scan_a<<<nsblk, 256, 0, stream>>>(cnt, partials, N);
    scan_b<<<1, 128, 0, stream>>>(partials, po, rowptr, nsblk, N);
    scan_c<<<nsblk, 256, 0, stream>>>(cnt, po, rowptr, cursor, dinv, N);
    fill_kernel<<<(E + 255) / 256, 256, 0, stream>>>(src, dst, cursor, colarr, E);

    // layer 1: h1g = (x @ W1) * dinv ; h1out = relu(dinv*(gather-sum + self) + b1)
    gemm_scale<64, 128, 8, 4, 32><<<(N + 63) / 64, 256, 0, stream>>>(x, W1, dinv, h1g, N, K1);
    agg_f2<<<(N + 3) / 4, 256, 0, stream>>>((const float2*)h1g, rowptr, colarr, dinv, b1,
                                            (float2*)h1out, N);

    // layer 2: h2g = (h1out @ W2) * dinv ; out = relu(dinv*(gather-sum + self) + b2)
    gemm_scale<64, 64, 4, 4, 32><<<(N + 63) / 64, 256, 0, stream>>>(h1out, W2, dinv, h2g, N, H1);
    agg_f1<<<(N + 3) / 4, 256, 0, stream>>>(h2g, rowptr, colarr, dinv, b2, out, N);
}

// Round 2
// 607.040 us; speedup vs baseline: 1.2466x; 1.2466x over previous
//
#include <hip/hip_runtime.h>

// ---------------- problem constants ----------------
#define NNODES 100000

// ---------------- workspace layout (bytes) ----------------
// cnt/cursor regions are dead after CSR build; W-split tables reuse OFF_CNT.
#define OFF_CNT      0UL            // int[100000] (later: W split tables)
#define OFF_W1TH     0UL            // ushort[128*256] = 65536
#define OFF_W1TL     65536UL        // ushort[128*256]
#define OFF_W2TH     131072UL       // ushort[64*128] = 16384
#define OFF_W2TL     147456UL       // ushort[64*128]  -> ends 163840 (< 400128)
#define OFF_ROWPTR   400128UL       // int[100001]
#define OFF_CURSOR   800384UL       // int[100000]
#define OFF_DINV     1200640UL      // float[100000]
#define OFF_PART     1600896UL      // int[128]
#define OFF_PO       1603072UL      // int[128]
#define OFF_COL      1605632UL      // int[1600000]  -> ends 8005632
#define OFF_H1G      8005632UL      // float[100000*128] -> ends 59205632
#define OFF_H1OUT    59205632UL     // float[100000*128] -> ends 110405632
// h2g reuses OFF_H1G (h1g dead after agg1)

typedef __attribute__((ext_vector_type(8))) short bf16x8;
typedef __attribute__((ext_vector_type(4))) float f32x4;

__device__ inline ushort f2bf(float f) {
    unsigned u = __float_as_uint(f);
    unsigned r = u + 0x7fffu + ((u >> 16) & 1u);  // round-to-nearest-even
    return (ushort)(r >> 16);
}
__device__ inline float bf2f(ushort h) { return __uint_as_float(((unsigned)h) << 16); }

// ---------------- degree count ----------------
__global__ __launch_bounds__(256) void count_kernel(const int* __restrict__ dst,
                                                    int* __restrict__ cnt, int E) {
    int i = blockIdx.x * 256 + threadIdx.x;
    if (i < E) atomicAdd(&cnt[dst[i]], 1);
}

// ---------------- prefix scan (3 phases) ----------------
__global__ __launch_bounds__(256) void scan_a(const int* __restrict__ cnt,
                                              int* __restrict__ partials, int n) {
    __shared__ int sdata[256];
    int t = threadIdx.x;
    int base = blockIdx.x * 1024 + t * 4;
    int s = 0;
#pragma unroll
    for (int i = 0; i < 4; ++i) {
        int idx = base + i;
        if (idx < n) s += cnt[idx];
    }
    sdata[t] = s;
    __syncthreads();
    for (int off = 128; off > 0; off >>= 1) {
        if (t < off) sdata[t] += sdata[t + off];
        __syncthreads();
    }
    if (t == 0) partials[blockIdx.x] = sdata[0];
}

__global__ __launch_bounds__(128) void scan_b(const int* __restrict__ partials,
                                              int* __restrict__ po,
                                              int* __restrict__ rowptr,
                                              int nblocks, int n) {
    __shared__ int s[128];
    int t = threadIdx.x;
    int v = (t < nblocks) ? partials[t] : 0;
    s[t] = v;
    __syncthreads();
    for (int off = 1; off < 128; off <<= 1) {
        int add = (t >= off) ? s[t - off] : 0;
        __syncthreads();
        s[t] += add;
        __syncthreads();
    }
    if (t < nblocks) po[t] = s[t] - v;  // exclusive
    if (t == 127) rowptr[n] = s[127];   // total = E
}

__global__ __launch_bounds__(256) void scan_c(const int* __restrict__ cnt,
                                              const int* __restrict__ po,
                                              int* __restrict__ rowptr,
                                              int* __restrict__ cursor,
                                              float* __restrict__ dinv, int n) {
    __shared__ int sdata[256];
    int t = threadIdx.x;
    int base = blockIdx.x * 1024 + t * 4;
    int v[4];
    int s = 0;
#pragma unroll
    for (int i = 0; i < 4; ++i) {
        int idx = base + i;
        v[i] = (idx < n) ? cnt[idx] : 0;
        s += v[i];
    }
    sdata[t] = s;
    __syncthreads();
    int own = s;
    for (int off = 1; off < 256; off <<= 1) {
        int add = (t >= off) ? sdata[t - off] : 0;
        __syncthreads();
        sdata[t] += add;
        __syncthreads();
    }
    int offset = po[blockIdx.x] + sdata[t] - own;
#pragma unroll
    for (int i = 0; i < 4; ++i) {
        int idx = base + i;
        if (idx < n) {
            rowptr[idx] = offset;
            cursor[idx] = offset;
            dinv[idx] = rsqrtf((float)(v[i] + 1));  // +1 self-loop
            offset += v[i];
        }
    }
}

__global__ __launch_bounds__(256) void fill_kernel(const int* __restrict__ src,
                                                   const int* __restrict__ dst,
                                                   int* __restrict__ cursor,
                                                   int* __restrict__ colarr, int E) {
    int i = blockIdx.x * 256 + threadIdx.x;
    if (i < E) {
        int d = dst[i];
        int slot = atomicAdd(&cursor[d], 1);
        colarr[slot] = src[i];
    }
}

// ---------------- split W [K][N] fp32 -> transposed bf16 hi/lo [N][K] ----------------
__global__ __launch_bounds__(256) void split_wt(const float* __restrict__ W,
                                                ushort* __restrict__ hi,
                                                ushort* __restrict__ lo,
                                                int K, int N) {
    int idx = blockIdx.x * 256 + threadIdx.x;
    if (idx >= K * N) return;
    int k = idx / N, n = idx - k * N;
    float v = W[idx];
    ushort h = f2bf(v);
    float rest = v - bf2f(h);
    hi[(size_t)n * K + k] = h;
    lo[(size_t)n * K + k] = f2bf(rest);
}

// ---------------- split-bf16 MFMA GEMM ----------------
// C[m][n] = (sum_k A[m][k]*W[k][n]) * dinv[m]
// A: [M][KTOT] fp32 (converted to hi/lo bf16 while staging)
// Bt: [BN][KTOT] bf16 hi/lo (pre-split, pre-transposed)
// block = 256 thr = 4 waves; block tile 128(M) x BN; wave tile 32(M) x BN.
template <int BN, int KTOT>
__global__ __launch_bounds__(256) void gemm_mfma(const float* __restrict__ A,
                                                 const ushort* __restrict__ Bh_g,
                                                 const ushort* __restrict__ Bl_g,
                                                 const float* __restrict__ dinv,
                                                 float* __restrict__ C, int M) {
    constexpr int KC = 64;
    constexpr int LDK = KC + 8;  // 144 B row stride: 16B-aligned, 2-way bank alias (free)
    __shared__ ushort Ah[128][LDK];
    __shared__ ushort Al[128][LDK];
    __shared__ ushort Bh[BN][LDK];
    __shared__ ushort Bl[BN][LDK];

    const int tid = threadIdx.x;
    const int wave = tid >> 6;
    const int lane = tid & 63;
    const int lm = lane & 15;  // row (A) / col (B,C) within 16x16 tile
    const int q = lane >> 4;   // 0..3
    const int m0 = blockIdx.x * 128;

    constexpr int NT = BN / 16;
    f32x4 acc[2][NT];
#pragma unroll
    for (int a = 0; a < 2; ++a)
#pragma unroll
        for (int b = 0; b < NT; ++b) acc[a][b] = (f32x4){0.f, 0.f, 0.f, 0.f};

    for (int k0 = 0; k0 < KTOT; k0 += KC) {
        // ---- stage A tile (fp32 -> split bf16): 128 x 64 ----
#pragma unroll
        for (int i = 0; i < 8; ++i) {
            int v = tid + i * 256;
            int row = v >> 4;           // 16 float4 per row
            int kk = (v & 15) << 2;
            int gr = m0 + row;
            float4 val = make_float4(0.f, 0.f, 0.f, 0.f);
            if (gr < M) val = *(const float4*)&A[(size_t)gr * KTOT + k0 + kk];
            ushort h0 = f2bf(val.x), h1 = f2bf(val.y), h2 = f2bf(val.z), h3 = f2bf(val.w);
            *(ushort4*)&Ah[row][kk] = make_ushort4(h0, h1, h2, h3);
            *(ushort4*)&Al[row][kk] = make_ushort4(
                f2bf(val.x - bf2f(h0)), f2bf(val.y - bf2f(h1)),
                f2bf(val.z - bf2f(h2)), f2bf(val.w - bf2f(h3)));
        }
        // ---- stage Bt tile (already bf16): BN x 64 ----
        constexpr int BV = BN * KC / 8 / 256;
#pragma unroll
        for (int i = 0; i < BV; ++i) {
            int v = tid + i * 256;
            int row = v >> 3;           // 8 x (8 ushorts) per row
            int kk = (v & 7) << 3;
            *(uint4*)&Bh[row][kk] = *(const uint4*)&Bh_g[(size_t)row * KTOT + k0 + kk];
            *(uint4*)&Bl[row][kk] = *(const uint4*)&Bl_g[(size_t)row * KTOT + k0 + kk];
        }
        __syncthreads();

#pragma unroll
        for (int ks = 0; ks < KC / 32; ++ks) {
            int kb = ks * 32 + q * 8;
            bf16x8 a_h[2], a_l[2];
#pragma unroll
            for (int mt = 0; mt < 2; ++mt) {
                int r = wave * 32 + mt * 16 + lm;
                a_h[mt] = *(const bf16x8*)&Ah[r][kb];
                a_l[mt] = *(const bf16x8*)&Al[r][kb];
            }
#pragma unroll
            for (int nt = 0; nt < NT; ++nt) {
                int c = nt * 16 + lm;
                bf16x8 b_h = *(const bf16x8*)&Bh[c][kb];
                bf16x8 b_l = *(const bf16x8*)&Bl[c][kb];
#pragma unroll
                for (int mt = 0; mt < 2; ++mt) {
                    acc[mt][nt] = __builtin_amdgcn_mfma_f32_16x16x32_bf16(a_h[mt], b_h, acc[mt][nt], 0, 0, 0);
                    acc[mt][nt] = __builtin_amdgcn_mfma_f32_16x16x32_bf16(a_h[mt], b_l, acc[mt][nt], 0, 0, 0);
                    acc[mt][nt] = __builtin_amdgcn_mfma_f32_16x16x32_bf16(a_l[mt], b_h, acc[mt][nt], 0, 0, 0);
                }
            }
        }
        __syncthreads();
    }

    // ---- epilogue: scale by dinv[row], store ----
#pragma unroll
    for (int mt = 0; mt < 2; ++mt) {
#pragma unroll
        for (int i = 0; i < 4; ++i) {
            int r = m0 + wave * 32 + mt * 16 + q * 4 + i;
            if (r < M) {
                float dv = dinv[r];
#pragma unroll
                for (int nt = 0; nt < NT; ++nt) {
                    C[(size_t)r * BN + nt * 16 + lm] = acc[mt][nt][i] * dv;
                }
            }
        }
    }
}

// ---------------- aggregation: out[n] = relu(dinv[n]*(sum_nbr g[src] + g[n]) + b) ----------------
__global__ __launch_bounds__(256) void agg_f2(const float2* __restrict__ g,
                                              const int* __restrict__ rowptr,
                                              const int* __restrict__ colarr,
                                              const float* __restrict__ dinv,
                                              const float* __restrict__ bias,
                                              float2* __restrict__ out, int n) {
    int node = blockIdx.x * 4 + (threadIdx.x >> 6);
    int lane = threadIdx.x & 63;
    if (node >= n) return;
    int beg = rowptr[node];
    int end = rowptr[node + 1];
    float2 acc = g[(size_t)node * 64 + lane];  // self loop
    int p = beg;
    for (; p + 4 <= end; p += 4) {
        int s0 = colarr[p], s1 = colarr[p + 1], s2 = colarr[p + 2], s3 = colarr[p + 3];
        float2 v0 = g[(size_t)s0 * 64 + lane];
        float2 v1 = g[(size_t)s1 * 64 + lane];
        float2 v2 = g[(size_t)s2 * 64 + lane];
        float2 v3 = g[(size_t)s3 * 64 + lane];
        acc.x += (v0.x + v1.x) + (v2.x + v3.x);
        acc.y += (v0.y + v1.y) + (v2.y + v3.y);
    }
    for (; p < end; ++p) {
        float2 v = g[(size_t)colarr[p] * 64 + lane];
        acc.x += v.x;
        acc.y += v.y;
    }
    float dv = dinv[node];
    float2 b = ((const float2*)bias)[lane];
    float2 o;
    o.x = fmaxf(fmaf(acc.x, dv, b.x), 0.f);
    o.y = fmaxf(fmaf(acc.y, dv, b.y), 0.f);
    out[(size_t)node * 64 + lane] = o;
}

__global__ __launch_bounds__(256) void agg_f1(const float* __restrict__ g,
                                              const int* __restrict__ rowptr,
                                              const int* __restrict__ colarr,
                                              const float* __restrict__ dinv,
                                              const float* __restrict__ bias,
                                              float* __restrict__ out, int n) {
    int node = blockIdx.x * 4 + (threadIdx.x >> 6);
    int lane = threadIdx.x & 63;
    if (node >= n) return;
    int beg = rowptr[node];
    int end = rowptr[node + 1];
    float acc = g[(size_t)node * 64 + lane];  // self loop
    int p = beg;
    for (; p + 4 <= end; p += 4) {
        int s0 = colarr[p], s1 = colarr[p + 1], s2 = colarr[p + 2], s3 = colarr[p + 3];
        float v0 = g[(size_t)s0 * 64 + lane];
        float v1 = g[(size_t)s1 * 64 + lane];
        float v2 = g[(size_t)s2 * 64 + lane];
        float v3 = g[(size_t)s3 * 64 + lane];
        acc += (v0 + v1) + (v2 + v3);
    }
    for (; p < end; ++p) acc += g[(size_t)colarr[p] * 64 + lane];
    float dv = dinv[node];
    float o = fmaxf(fmaf(acc, dv, bias[lane]), 0.f);
    out[(size_t)node * 64 + lane] = o;
}

extern "C" void kernel_launch(void* const* d_in, const int* in_sizes, int n_in,
                              void* d_out, int out_size, void* d_ws, size_t ws_size,
                              hipStream_t stream) {
    const float* x  = (const float*)d_in[0];
    const int*   ei = (const int*)d_in[1];
    const float* W1 = (const float*)d_in[2];
    const float* b1 = (const float*)d_in[3];
    const float* W2 = (const float*)d_in[4];
    const float* b2 = (const float*)d_in[5];
    float* out = (float*)d_out;

    const int E = in_sizes[1] / 2;
    const int H1 = in_sizes[3];                 // 128
    const int K1 = in_sizes[2] / H1;            // 256
    const int N = in_sizes[0] / K1;             // 100000
    const int H2 = in_sizes[4] / H1;            // 64
    const int* src = ei;
    const int* dst = ei + E;

    char* ws = (char*)d_ws;
    int*    cnt      = (int*)(ws + OFF_CNT);
    ushort* w1th     = (ushort*)(ws + OFF_W1TH);
    ushort* w1tl     = (ushort*)(ws + OFF_W1TL);
    ushort* w2th     = (ushort*)(ws + OFF_W2TH);
    ushort* w2tl     = (ushort*)(ws + OFF_W2TL);
    int*    rowptr   = (int*)(ws + OFF_ROWPTR);
    int*    cursor   = (int*)(ws + OFF_CURSOR);
    float*  dinv     = (float*)(ws + OFF_DINV);
    int*    partials = (int*)(ws + OFF_PART);
    int*    po       = (int*)(ws + OFF_PO);
    int*    colarr   = (int*)(ws + OFF_COL);
    float*  h1g      = (float*)(ws + OFF_H1G);
    float*  h1out    = (float*)(ws + OFF_H1OUT);
    float*  h2g      = (float*)(ws + OFF_H1G);   // reuse

    hipMemsetAsync(cnt, 0, (size_t)N * sizeof(int), stream);
    count_kernel<<<(E + 255) / 256, 256, 0, stream>>>(dst, cnt, E);

    int nsblk = (N + 1023) / 1024;
    scan_a<<<nsblk, 256, 0, stream>>>(cnt, partials, N);
    scan_b<<<1, 128, 0, stream>>>(partials, po, rowptr, nsblk, N);
    scan_c<<<nsblk, 256, 0, stream>>>(cnt, po, rowptr, cursor, dinv, N);
    fill_kernel<<<(E + 255) / 256, 256, 0, stream>>>(src, dst, cursor, colarr, E);

    // W split tables (overwrite dead cnt region — only after scan_c consumed cnt)
    split_wt<<<(K1 * H1 + 255) / 256, 256, 0, stream>>>(W1, w1th, w1tl, K1, H1);
    split_wt<<<(H1 * H2 + 255) / 256, 256, 0, stream>>>(W2, w2th, w2tl, H1, H2);

    // layer 1
    gemm_mfma<128, 256><<<(N + 127) / 128, 256, 0, stream>>>(x, w1th, w1tl, dinv, h1g, N);
    agg_f2<<<(N + 3) / 4, 256, 0, stream>>>((const float2*)h1g, rowptr, colarr, dinv, b1,
                                            (float2*)h1out, N);

    // layer 2
    gemm_mfma<64, 128><<<(N + 127) / 128, 256, 0, stream>>>(h1out, w2th, w2tl, dinv, h2g, N);
    agg_f1<<<(N + 3) / 4, 256, 0, stream>>>(h2g, rowptr, colarr, dinv, b2, out, N);
}

// Round 3
// 493.156 us; speedup vs baseline: 1.5345x; 1.2309x over previous
//
#include <hip/hip_runtime.h>

// ---------------- problem constants ----------------
#define NNODES 100000

// ---------------- workspace layout (bytes) ----------------
#define OFF_W1TH     0UL            // ushort[128*256] = 65536
#define OFF_W1TL     65536UL        // ushort[128*256]
#define OFF_W2TH     131072UL       // ushort[64*128] = 16384
#define OFF_W2TL     147456UL       // ushort[64*128]  -> ends 163840
#define OFF_BCNT     163840UL       // int[512]
#define OFF_BBASE    165888UL       // int[512]
#define OFF_BCUR     167936UL       // int[512] -> ends 169984
#define OFF_ROWPTR   400128UL       // int[100001]
#define OFF_DINV     1200640UL      // float[100000]
#define OFF_COL      1605632UL      // int[1600000]  -> ends 8005632
#define OFF_EBUF     8005632UL      // int2[1600000] = 12.8MB (overlaps h1g; dead before gemm1)
#define OFF_H1G      8005632UL      // float[100000*128] -> ends 59205632
#define OFF_H1OUT    59205632UL     // float[100000*128] -> ends 110405632
// h2g reuses OFF_H1G (h1g dead after agg1)

typedef __attribute__((ext_vector_type(8))) short bf16x8;
typedef __attribute__((ext_vector_type(4))) float f32x4;

__device__ inline ushort f2bf(float f) {
    unsigned u = __float_as_uint(f);
    unsigned r = u + 0x7fffu + ((u >> 16) & 1u);  // round-to-nearest-even
    return (ushort)(r >> 16);
}
__device__ inline float bf2f(ushort h) { return __uint_as_float(((unsigned)h) << 16); }

// =========== CSR build via 2-level counting sort (bucket = dst>>8) ===========
// Phase A: per-bucket histogram, LDS-staged
__global__ __launch_bounds__(256) void bincount(const int* __restrict__ dst,
                                                int* __restrict__ bcnt, int E) {
    __shared__ int lc[512];
    int t = threadIdx.x;
    lc[t] = 0; lc[t + 256] = 0;
    __syncthreads();
    for (int e = blockIdx.x * 256 + t; e < E; e += gridDim.x * 256)
        atomicAdd(&lc[dst[e] >> 8], 1);
    __syncthreads();
    if (lc[t]) atomicAdd(&bcnt[t], lc[t]);
    if (lc[t + 256]) atomicAdd(&bcnt[t + 256], lc[t + 256]);
}

// Phase B: scan bucket counts (NB <= 512), init cursors, write rowptr sentinel
__global__ __launch_bounds__(512) void bscan(const int* __restrict__ bcnt,
                                             int* __restrict__ bbase,
                                             int* __restrict__ bcur,
                                             int* __restrict__ rowptr,
                                             int NB, int N, int E) {
    __shared__ int s[512];
    int t = threadIdx.x;
    int v = (t < NB) ? bcnt[t] : 0;
    s[t] = v;
    __syncthreads();
    for (int off = 1; off < 512; off <<= 1) {
        int add = (t >= off) ? s[t - off] : 0;
        __syncthreads();
        s[t] += add;
        __syncthreads();
    }
    if (t < NB) {
        int ex = s[t] - v;
        bbase[t] = ex;
        bcur[t] = ex;
    }
    if (t == 0) rowptr[N] = E;
}

// Phase C: bucket-grouped scatter of (src,dst) pairs. Each block locally ranks
// its 4096-edge chunk per bucket, then writes runs of contiguous pairs.
#define CHUNK 4096
__global__ __launch_bounds__(256) void binscatter(const int* __restrict__ src,
                                                  const int* __restrict__ dst,
                                                  int* __restrict__ bcur,
                                                  int2* __restrict__ ebuf, int E) {
    __shared__ int lc[512];
    __shared__ int gb[512];
    int t = threadIdx.x;
    lc[t] = 0; lc[t + 256] = 0;
    __syncthreads();
    int base = blockIdx.x * CHUNK;
    int rb[16];
#pragma unroll
    for (int i = 0; i < 16; ++i) {
        int e = base + i * 256 + t;
        if (e < E) {
            int b = dst[e] >> 8;
            rb[i] = (b << 12) | atomicAdd(&lc[b], 1);  // rank < 4096 fits 12 bits
        } else rb[i] = -1;
    }
    __syncthreads();
    if (lc[t]) gb[t] = atomicAdd(&bcur[t], lc[t]);
    if (lc[t + 256]) gb[t + 256] = atomicAdd(&bcur[t + 256], lc[t + 256]);
    __syncthreads();
#pragma unroll
    for (int i = 0; i < 16; ++i) {
        if (rb[i] >= 0) {
            int e = base + i * 256 + t;
            int b = rb[i] >> 12, r = rb[i] & 4095;
            ebuf[gb[b] + r] = make_int2(src[e], dst[e]);
        }
    }
}

// Phase D: one block per bucket — per-node count/scan in LDS -> rowptr/dinv,
// then fine scatter into an L2-resident ~16KB colarr window.
__global__ __launch_bounds__(256) void buildcsr(const int2* __restrict__ ebuf,
                                                const int* __restrict__ bbase,
                                                const int* __restrict__ bcnt,
                                                int* __restrict__ rowptr,
                                                int* __restrict__ colarr,
                                                float* __restrict__ dinv, int N) {
    int b = blockIdx.x;
    int t = threadIdx.x;
    int start = bbase[b];
    int cnt = bcnt[b];
    int n0 = b << 8;
    __shared__ int nc[256];
    __shared__ int s[256];
    __shared__ int ncur[256];
    nc[t] = 0;
    __syncthreads();
    for (int e = t; e < cnt; e += 256) atomicAdd(&nc[ebuf[start + e].y - n0], 1);
    __syncthreads();
    int own = nc[t];
    s[t] = own;
    __syncthreads();
    for (int off = 1; off < 256; off <<= 1) {
        int add = (t >= off) ? s[t - off] : 0;
        __syncthreads();
        s[t] += add;
        __syncthreads();
    }
    int rowbase = start + s[t] - own;
    if (n0 + t < N) {
        rowptr[n0 + t] = rowbase;
        dinv[n0 + t] = rsqrtf((float)(own + 1));  // +1 self-loop
    }
    ncur[t] = rowbase;
    __syncthreads();
    for (int e = t; e < cnt; e += 256) {
        int2 p = ebuf[start + e];
        int slot = atomicAdd(&ncur[p.y - n0], 1);
        colarr[slot] = p.x;
    }
}

// ---------------- split W [K][N] fp32 -> transposed bf16 hi/lo [N][K] ----------------
__global__ __launch_bounds__(256) void split_wt(const float* __restrict__ W,
                                                ushort* __restrict__ hi,
                                                ushort* __restrict__ lo,
                                                int K, int N) {
    int idx = blockIdx.x * 256 + threadIdx.x;
    if (idx >= K * N) return;
    int k = idx / N, n = idx - k * N;
    float v = W[idx];
    ushort h = f2bf(v);
    float rest = v - bf2f(h);
    hi[(size_t)n * K + k] = h;
    lo[(size_t)n * K + k] = f2bf(rest);
}

// ---------------- split-bf16 MFMA GEMM ----------------
template <int BN, int KTOT>
__global__ __launch_bounds__(256) void gemm_mfma(const float* __restrict__ A,
                                                 const ushort* __restrict__ Bh_g,
                                                 const ushort* __restrict__ Bl_g,
                                                 const float* __restrict__ dinv,
                                                 float* __restrict__ C, int M) {
    constexpr int KC = 64;
    constexpr int LDK = KC + 8;
    __shared__ ushort Ah[128][LDK];
    __shared__ ushort Al[128][LDK];
    __shared__ ushort Bh[BN][LDK];
    __shared__ ushort Bl[BN][LDK];

    const int tid = threadIdx.x;
    const int wave = tid >> 6;
    const int lane = tid & 63;
    const int lm = lane & 15;
    const int q = lane >> 4;
    const int m0 = blockIdx.x * 128;

    constexpr int NT = BN / 16;
    f32x4 acc[2][NT];
#pragma unroll
    for (int a = 0; a < 2; ++a)
#pragma unroll
        for (int b = 0; b < NT; ++b) acc[a][b] = (f32x4){0.f, 0.f, 0.f, 0.f};

    for (int k0 = 0; k0 < KTOT; k0 += KC) {
#pragma unroll
        for (int i = 0; i < 8; ++i) {
            int v = tid + i * 256;
            int row = v >> 4;
            int kk = (v & 15) << 2;
            int gr = m0 + row;
            float4 val = make_float4(0.f, 0.f, 0.f, 0.f);
            if (gr < M) val = *(const float4*)&A[(size_t)gr * KTOT + k0 + kk];
            ushort h0 = f2bf(val.x), h1 = f2bf(val.y), h2 = f2bf(val.z), h3 = f2bf(val.w);
            *(ushort4*)&Ah[row][kk] = make_ushort4(h0, h1, h2, h3);
            *(ushort4*)&Al[row][kk] = make_ushort4(
                f2bf(val.x - bf2f(h0)), f2bf(val.y - bf2f(h1)),
                f2bf(val.z - bf2f(h2)), f2bf(val.w - bf2f(h3)));
        }
        constexpr int BV = BN * KC / 8 / 256;
#pragma unroll
        for (int i = 0; i < BV; ++i) {
            int v = tid + i * 256;
            int row = v >> 3;
            int kk = (v & 7) << 3;
            *(uint4*)&Bh[row][kk] = *(const uint4*)&Bh_g[(size_t)row * KTOT + k0 + kk];
            *(uint4*)&Bl[row][kk] = *(const uint4*)&Bl_g[(size_t)row * KTOT + k0 + kk];
        }
        __syncthreads();

#pragma unroll
        for (int ks = 0; ks < KC / 32; ++ks) {
            int kb = ks * 32 + q * 8;
            bf16x8 a_h[2], a_l[2];
#pragma unroll
            for (int mt = 0; mt < 2; ++mt) {
                int r = wave * 32 + mt * 16 + lm;
                a_h[mt] = *(const bf16x8*)&Ah[r][kb];
                a_l[mt] = *(const bf16x8*)&Al[r][kb];
            }
#pragma unroll
            for (int nt = 0; nt < NT; ++nt) {
                int c = nt * 16 + lm;
                bf16x8 b_h = *(const bf16x8*)&Bh[c][kb];
                bf16x8 b_l = *(const bf16x8*)&Bl[c][kb];
#pragma unroll
                for (int mt = 0; mt < 2; ++mt) {
                    acc[mt][nt] = __builtin_amdgcn_mfma_f32_16x16x32_bf16(a_h[mt], b_h, acc[mt][nt], 0, 0, 0);
                    acc[mt][nt] = __builtin_amdgcn_mfma_f32_16x16x32_bf16(a_h[mt], b_l, acc[mt][nt], 0, 0, 0);
                    acc[mt][nt] = __builtin_amdgcn_mfma_f32_16x16x32_bf16(a_l[mt], b_h, acc[mt][nt], 0, 0, 0);
                }
            }
        }
        __syncthreads();
    }

#pragma unroll
    for (int mt = 0; mt < 2; ++mt) {
#pragma unroll
        for (int i = 0; i < 4; ++i) {
            int r = m0 + wave * 32 + mt * 16 + q * 4 + i;
            if (r < M) {
                float dv = dinv[r];
#pragma unroll
                for (int nt = 0; nt < NT; ++nt) {
                    C[(size_t)r * BN + nt * 16 + lm] = acc[mt][nt][i] * dv;
                }
            }
        }
    }
}

// ---------------- aggregation ----------------
__global__ __launch_bounds__(256) void agg_f2(const float2* __restrict__ g,
                                              const int* __restrict__ rowptr,
                                              const int* __restrict__ colarr,
                                              const float* __restrict__ dinv,
                                              const float* __restrict__ bias,
                                              float2* __restrict__ out, int n) {
    int node = blockIdx.x * 4 + (threadIdx.x >> 6);
    int lane = threadIdx.x & 63;
    if (node >= n) return;
    int beg = rowptr[node];
    int end = rowptr[node + 1];
    float2 acc = g[(size_t)node * 64 + lane];
    int p = beg;
    for (; p + 4 <= end; p += 4) {
        int s0 = colarr[p], s1 = colarr[p + 1], s2 = colarr[p + 2], s3 = colarr[p + 3];
        float2 v0 = g[(size_t)s0 * 64 + lane];
        float2 v1 = g[(size_t)s1 * 64 + lane];
        float2 v2 = g[(size_t)s2 * 64 + lane];
        float2 v3 = g[(size_t)s3 * 64 + lane];
        acc.x += (v0.x + v1.x) + (v2.x + v3.x);
        acc.y += (v0.y + v1.y) + (v2.y + v3.y);
    }
    for (; p < end; ++p) {
        float2 v = g[(size_t)colarr[p] * 64 + lane];
        acc.x += v.x;
        acc.y += v.y;
    }
    float dv = dinv[node];
    float2 b = ((const float2*)bias)[lane];
    float2 o;
    o.x = fmaxf(fmaf(acc.x, dv, b.x), 0.f);
    o.y = fmaxf(fmaf(acc.y, dv, b.y), 0.f);
    out[(size_t)node * 64 + lane] = o;
}

__global__ __launch_bounds__(256) void agg_f1(const float* __restrict__ g,
                                              const int* __restrict__ rowptr,
                                              const int* __restrict__ colarr,
                                              const float* __restrict__ dinv,
                                              const float* __restrict__ bias,
                                              float* __restrict__ out, int n) {
    int node = blockIdx.x * 4 + (threadIdx.x >> 6);
    int lane = threadIdx.x & 63;
    if (node >= n) return;
    int beg = rowptr[node];
    int end = rowptr[node + 1];
    float acc = g[(size_t)node * 64 + lane];
    int p = beg;
    for (; p + 4 <= end; p += 4) {
        int s0 = colarr[p], s1 = colarr[p + 1], s2 = colarr[p + 2], s3 = colarr[p + 3];
        float v0 = g[(size_t)s0 * 64 + lane];
        float v1 = g[(size_t)s1 * 64 + lane];
        float v2 = g[(size_t)s2 * 64 + lane];
        float v3 = g[(size_t)s3 * 64 + lane];
        acc += (v0 + v1) + (v2 + v3);
    }
    for (; p < end; ++p) acc += g[(size_t)colarr[p] * 64 + lane];
    float dv = dinv[node];
    float o = fmaxf(fmaf(acc, dv, bias[lane]), 0.f);
    out[(size_t)node * 64 + lane] = o;
}

extern "C" void kernel_launch(void* const* d_in, const int* in_sizes, int n_in,
                              void* d_out, int out_size, void* d_ws, size_t ws_size,
                              hipStream_t stream) {
    const float* x  = (const float*)d_in[0];
    const int*   ei = (const int*)d_in[1];
    const float* W1 = (const float*)d_in[2];
    const float* b1 = (const float*)d_in[3];
    const float* W2 = (const float*)d_in[4];
    const float* b2 = (const float*)d_in[5];
    float* out = (float*)d_out;

    const int E = in_sizes[1] / 2;
    const int H1 = in_sizes[3];                 // 128
    const int K1 = in_sizes[2] / H1;            // 256
    const int N = in_sizes[0] / K1;             // 100000
    const int H2 = in_sizes[4] / H1;            // 64
    const int* src = ei;
    const int* dst = ei + E;
    const int NB = (N + 255) >> 8;              // 391 buckets

    char* ws = (char*)d_ws;
    ushort* w1th   = (ushort*)(ws + OFF_W1TH);
    ushort* w1tl   = (ushort*)(ws + OFF_W1TL);
    ushort* w2th   = (ushort*)(ws + OFF_W2TH);
    ushort* w2tl   = (ushort*)(ws + OFF_W2TL);
    int*    bcnt   = (int*)(ws + OFF_BCNT);
    int*    bbase  = (int*)(ws + OFF_BBASE);
    int*    bcur   = (int*)(ws + OFF_BCUR);
    int*    rowptr = (int*)(ws + OFF_ROWPTR);
    float*  dinv   = (float*)(ws + OFF_DINV);
    int*    colarr = (int*)(ws + OFF_COL);
    int2*   ebuf   = (int2*)(ws + OFF_EBUF);
    float*  h1g    = (float*)(ws + OFF_H1G);
    float*  h1out  = (float*)(ws + OFF_H1OUT);
    float*  h2g    = (float*)(ws + OFF_H1G);    // reuse

    hipMemsetAsync(bcnt, 0, 512 * sizeof(int), stream);
    bincount<<<256, 256, 0, stream>>>(dst, bcnt, E);
    bscan<<<1, 512, 0, stream>>>(bcnt, bbase, bcur, rowptr, NB, N, E);
    binscatter<<<(E + CHUNK - 1) / CHUNK, 256, 0, stream>>>(src, dst, bcur, ebuf, E);
    buildcsr<<<NB, 256, 0, stream>>>(ebuf, bbase, bcnt, rowptr, colarr, dinv, N);

    split_wt<<<(K1 * H1 + 255) / 256, 256, 0, stream>>>(W1, w1th, w1tl, K1, H1);
    split_wt<<<(H1 * H2 + 255) / 256, 256, 0, stream>>>(W2, w2th, w2tl, H1, H2);

    // layer 1
    gemm_mfma<128, 256><<<(N + 127) / 128, 256, 0, stream>>>(x, w1th, w1tl, dinv, h1g, N);
    agg_f2<<<(N + 3) / 4, 256, 0, stream>>>((const float2*)h1g, rowptr, colarr, dinv, b1,
                                            (float2*)h1out, N);

    // layer 2
    gemm_mfma<64, 128><<<(N + 127) / 128, 256, 0, stream>>>(h1out, w2th, w2tl, dinv, h2g, N);
    agg_f1<<<(N + 3) / 4, 256, 0, stream>>>(h2g, rowptr, colarr, dinv, b2, out, N);
}

// Round 4
// 444.943 us; speedup vs baseline: 1.7007x; 1.1084x over previous
//
#include <hip/hip_runtime.h>
#include <hip/hip_fp16.h>

// ---------------- problem constants ----------------
#define NNODES 100000

// ---------------- workspace layout (bytes) ----------------
#define OFF_W1TH     0UL            // ushort[128*256] = 65536
#define OFF_W1TL     65536UL        // ushort[128*256]
#define OFF_W2TH     131072UL       // ushort[64*128] = 16384
#define OFF_W2TL     147456UL       // ushort[64*128]  -> ends 163840
#define OFF_BCNT     163840UL       // int[512]
#define OFF_BBASE    165888UL       // int[512]
#define OFF_BCUR     167936UL       // int[512] -> ends 169984
#define OFF_ROWPTR   400128UL       // int[100001]
#define OFF_DINV     1200640UL      // float[100000]
#define OFF_COL      1605632UL      // int[1600000]  -> ends 8005632
#define OFF_EBUF     8005632UL      // int2[1600000] = 12.8MB (overlaps h1g; dead before gemm1)
#define OFF_H1G      8005632UL      // half[100000*128] = 25.6MB -> ends 33605632
#define OFF_H1OUT    59205632UL     // float[100000*128] -> ends 110405632
// h2g (half[100000*64]) reuses OFF_H1G (h1g dead after agg1)

typedef __attribute__((ext_vector_type(8))) short bf16x8;
typedef __attribute__((ext_vector_type(4))) float f32x4;

__device__ inline ushort f2bf(float f) {
    unsigned u = __float_as_uint(f);
    unsigned r = u + 0x7fffu + ((u >> 16) & 1u);  // round-to-nearest-even
    return (ushort)(r >> 16);
}
__device__ inline float bf2f(ushort h) { return __uint_as_float(((unsigned)h) << 16); }

// =========== CSR build via 2-level counting sort (bucket = dst>>8) ===========
__global__ __launch_bounds__(256) void bincount(const int* __restrict__ dst,
                                                int* __restrict__ bcnt, int E) {
    __shared__ int lc[512];
    int t = threadIdx.x;
    lc[t] = 0; lc[t + 256] = 0;
    __syncthreads();
    for (int e = blockIdx.x * 256 + t; e < E; e += gridDim.x * 256)
        atomicAdd(&lc[dst[e] >> 8], 1);
    __syncthreads();
    if (lc[t]) atomicAdd(&bcnt[t], lc[t]);
    if (lc[t + 256]) atomicAdd(&bcnt[t + 256], lc[t + 256]);
}

__global__ __launch_bounds__(512) void bscan(const int* __restrict__ bcnt,
                                             int* __restrict__ bbase,
                                             int* __restrict__ bcur,
                                             int* __restrict__ rowptr,
                                             int NB, int N, int E) {
    __shared__ int s[512];
    int t = threadIdx.x;
    int v = (t < NB) ? bcnt[t] : 0;
    s[t] = v;
    __syncthreads();
    for (int off = 1; off < 512; off <<= 1) {
        int add = (t >= off) ? s[t - off] : 0;
        __syncthreads();
        s[t] += add;
        __syncthreads();
    }
    if (t < NB) {
        int ex = s[t] - v;
        bbase[t] = ex;
        bcur[t] = ex;
    }
    if (t == 0) rowptr[N] = E;
}

#define CHUNK 4096
__global__ __launch_bounds__(256) void binscatter(const int* __restrict__ src,
                                                  const int* __restrict__ dst,
                                                  int* __restrict__ bcur,
                                                  int2* __restrict__ ebuf, int E) {
    __shared__ int lc[512];
    __shared__ int gb[512];
    int t = threadIdx.x;
    lc[t] = 0; lc[t + 256] = 0;
    __syncthreads();
    int base = blockIdx.x * CHUNK;
    int rb[16];
#pragma unroll
    for (int i = 0; i < 16; ++i) {
        int e = base + i * 256 + t;
        if (e < E) {
            int b = dst[e] >> 8;
            rb[i] = (b << 12) | atomicAdd(&lc[b], 1);
        } else rb[i] = -1;
    }
    __syncthreads();
    if (lc[t]) gb[t] = atomicAdd(&bcur[t], lc[t]);
    if (lc[t + 256]) gb[t + 256] = atomicAdd(&bcur[t + 256], lc[t + 256]);
    __syncthreads();
#pragma unroll
    for (int i = 0; i < 16; ++i) {
        if (rb[i] >= 0) {
            int e = base + i * 256 + t;
            int b = rb[i] >> 12, r = rb[i] & 4095;
            ebuf[gb[b] + r] = make_int2(src[e], dst[e]);
        }
    }
}

__global__ __launch_bounds__(256) void buildcsr(const int2* __restrict__ ebuf,
                                                const int* __restrict__ bbase,
                                                const int* __restrict__ bcnt,
                                                int* __restrict__ rowptr,
                                                int* __restrict__ colarr,
                                                float* __restrict__ dinv, int N) {
    int b = blockIdx.x;
    int t = threadIdx.x;
    int start = bbase[b];
    int cnt = bcnt[b];
    int n0 = b << 8;
    __shared__ int nc[256];
    __shared__ int s[256];
    __shared__ int ncur[256];
    nc[t] = 0;
    __syncthreads();
    for (int e = t; e < cnt; e += 256) atomicAdd(&nc[ebuf[start + e].y - n0], 1);
    __syncthreads();
    int own = nc[t];
    s[t] = own;
    __syncthreads();
    for (int off = 1; off < 256; off <<= 1) {
        int add = (t >= off) ? s[t - off] : 0;
        __syncthreads();
        s[t] += add;
        __syncthreads();
    }
    int rowbase = start + s[t] - own;
    if (n0 + t < N) {
        rowptr[n0 + t] = rowbase;
        dinv[n0 + t] = rsqrtf((float)(own + 1));
    }
    ncur[t] = rowbase;
    __syncthreads();
    for (int e = t; e < cnt; e += 256) {
        int2 p = ebuf[start + e];
        int slot = atomicAdd(&ncur[p.y - n0], 1);
        colarr[slot] = p.x;
    }
}

// ---------------- split W [K][N] fp32 -> transposed bf16 hi/lo [N][K] ----------------
__global__ __launch_bounds__(256) void split_wt(const float* __restrict__ W,
                                                ushort* __restrict__ hi,
                                                ushort* __restrict__ lo,
                                                int K, int N) {
    int idx = blockIdx.x * 256 + threadIdx.x;
    if (idx >= K * N) return;
    int k = idx / N, n = idx - k * N;
    float v = W[idx];
    ushort h = f2bf(v);
    float rest = v - bf2f(h);
    hi[(size_t)n * K + k] = h;
    lo[(size_t)n * K + k] = f2bf(rest);
}

// ---------------- split-bf16 MFMA GEMM; epilogue: *dinv[row], store fp16 ----------------
template <int BN, int KTOT>
__global__ __launch_bounds__(256) void gemm_mfma(const float* __restrict__ A,
                                                 const ushort* __restrict__ Bh_g,
                                                 const ushort* __restrict__ Bl_g,
                                                 const float* __restrict__ dinv,
                                                 _Float16* __restrict__ C, int M) {
    constexpr int KC = 64;
    constexpr int LDK = KC + 8;
    __shared__ ushort Ah[128][LDK];
    __shared__ ushort Al[128][LDK];
    __shared__ ushort Bh[BN][LDK];
    __shared__ ushort Bl[BN][LDK];

    const int tid = threadIdx.x;
    const int wave = tid >> 6;
    const int lane = tid & 63;
    const int lm = lane & 15;
    const int q = lane >> 4;
    const int m0 = blockIdx.x * 128;

    constexpr int NT = BN / 16;
    f32x4 acc[2][NT];
#pragma unroll
    for (int a = 0; a < 2; ++a)
#pragma unroll
        for (int b = 0; b < NT; ++b) acc[a][b] = (f32x4){0.f, 0.f, 0.f, 0.f};

    for (int k0 = 0; k0 < KTOT; k0 += KC) {
#pragma unroll
        for (int i = 0; i < 8; ++i) {
            int v = tid + i * 256;
            int row = v >> 4;
            int kk = (v & 15) << 2;
            int gr = m0 + row;
            float4 val = make_float4(0.f, 0.f, 0.f, 0.f);
            if (gr < M) val = *(const float4*)&A[(size_t)gr * KTOT + k0 + kk];
            ushort h0 = f2bf(val.x), h1 = f2bf(val.y), h2 = f2bf(val.z), h3 = f2bf(val.w);
            *(ushort4*)&Ah[row][kk] = make_ushort4(h0, h1, h2, h3);
            *(ushort4*)&Al[row][kk] = make_ushort4(
                f2bf(val.x - bf2f(h0)), f2bf(val.y - bf2f(h1)),
                f2bf(val.z - bf2f(h2)), f2bf(val.w - bf2f(h3)));
        }
        constexpr int BV = BN * KC / 8 / 256;
#pragma unroll
        for (int i = 0; i < BV; ++i) {
            int v = tid + i * 256;
            int row = v >> 3;
            int kk = (v & 7) << 3;
            *(uint4*)&Bh[row][kk] = *(const uint4*)&Bh_g[(size_t)row * KTOT + k0 + kk];
            *(uint4*)&Bl[row][kk] = *(const uint4*)&Bl_g[(size_t)row * KTOT + k0 + kk];
        }
        __syncthreads();

#pragma unroll
        for (int ks = 0; ks < KC / 32; ++ks) {
            int kb = ks * 32 + q * 8;
            bf16x8 a_h[2], a_l[2];
#pragma unroll
            for (int mt = 0; mt < 2; ++mt) {
                int r = wave * 32 + mt * 16 + lm;
                a_h[mt] = *(const bf16x8*)&Ah[r][kb];
                a_l[mt] = *(const bf16x8*)&Al[r][kb];
            }
#pragma unroll
            for (int nt = 0; nt < NT; ++nt) {
                int c = nt * 16 + lm;
                bf16x8 b_h = *(const bf16x8*)&Bh[c][kb];
                bf16x8 b_l = *(const bf16x8*)&Bl[c][kb];
#pragma unroll
                for (int mt = 0; mt < 2; ++mt) {
                    acc[mt][nt] = __builtin_amdgcn_mfma_f32_16x16x32_bf16(a_h[mt], b_h, acc[mt][nt], 0, 0, 0);
                    acc[mt][nt] = __builtin_amdgcn_mfma_f32_16x16x32_bf16(a_h[mt], b_l, acc[mt][nt], 0, 0, 0);
                    acc[mt][nt] = __builtin_amdgcn_mfma_f32_16x16x32_bf16(a_l[mt], b_h, acc[mt][nt], 0, 0, 0);
                }
            }
        }
        __syncthreads();
    }

#pragma unroll
    for (int mt = 0; mt < 2; ++mt) {
#pragma unroll
        for (int i = 0; i < 4; ++i) {
            int r = m0 + wave * 32 + mt * 16 + q * 4 + i;
            if (r < M) {
                float dv = dinv[r];
#pragma unroll
                for (int nt = 0; nt < NT; ++nt) {
                    C[(size_t)r * BN + nt * 16 + lm] = (_Float16)(acc[mt][nt][i] * dv);
                }
            }
        }
    }
}

// ---------------- aggregation (fp16 gather, fp32 accumulate) ----------------
// 128 channels: one wave per node, half2 (2ch) per lane; out fp32
__global__ __launch_bounds__(256) void agg_f2h(const __half2* __restrict__ g,
                                               const int* __restrict__ rowptr,
                                               const int* __restrict__ colarr,
                                               const float* __restrict__ dinv,
                                               const float* __restrict__ bias,
                                               float2* __restrict__ out, int n) {
    int node = blockIdx.x * 4 + (threadIdx.x >> 6);
    int lane = threadIdx.x & 63;
    if (node >= n) return;
    int beg = rowptr[node];
    int end = rowptr[node + 1];
    float2 acc = __half22float2(g[(size_t)node * 64 + lane]);  // self loop
    int p = beg;
    for (; p + 4 <= end; p += 4) {
        int s0 = colarr[p], s1 = colarr[p + 1], s2 = colarr[p + 2], s3 = colarr[p + 3];
        float2 v0 = __half22float2(g[(size_t)s0 * 64 + lane]);
        float2 v1 = __half22float2(g[(size_t)s1 * 64 + lane]);
        float2 v2 = __half22float2(g[(size_t)s2 * 64 + lane]);
        float2 v3 = __half22float2(g[(size_t)s3 * 64 + lane]);
        acc.x += (v0.x + v1.x) + (v2.x + v3.x);
        acc.y += (v0.y + v1.y) + (v2.y + v3.y);
    }
    for (; p < end; ++p) {
        float2 v = __half22float2(g[(size_t)colarr[p] * 64 + lane]);
        acc.x += v.x;
        acc.y += v.y;
    }
    float dv = dinv[node];
    float2 b = ((const float2*)bias)[lane];
    float2 o;
    o.x = fmaxf(fmaf(acc.x, dv, b.x), 0.f);
    o.y = fmaxf(fmaf(acc.y, dv, b.y), 0.f);
    out[(size_t)node * 64 + lane] = o;
}

// 64 channels: one wave per node, one half per lane; out fp32
__global__ __launch_bounds__(256) void agg_f1h(const _Float16* __restrict__ g,
                                               const int* __restrict__ rowptr,
                                               const int* __restrict__ colarr,
                                               const float* __restrict__ dinv,
                                               const float* __restrict__ bias,
                                               float* __restrict__ out, int n) {
    int node = blockIdx.x * 4 + (threadIdx.x >> 6);
    int lane = threadIdx.x & 63;
    if (node >= n) return;
    int beg = rowptr[node];
    int end = rowptr[node + 1];
    float acc = (float)g[(size_t)node * 64 + lane];  // self loop
    int p = beg;
    for (; p + 4 <= end; p += 4) {
        int s0 = colarr[p], s1 = colarr[p + 1], s2 = colarr[p + 2], s3 = colarr[p + 3];
        float v0 = (float)g[(size_t)s0 * 64 + lane];
        float v1 = (float)g[(size_t)s1 * 64 + lane];
        float v2 = (float)g[(size_t)s2 * 64 + lane];
        float v3 = (float)g[(size_t)s3 * 64 + lane];
        acc += (v0 + v1) + (v2 + v3);
    }
    for (; p < end; ++p) acc += (float)g[(size_t)colarr[p] * 64 + lane];
    float dv = dinv[node];
    float o = fmaxf(fmaf(acc, dv, bias[lane]), 0.f);
    out[(size_t)node * 64 + lane] = o;
}

extern "C" void kernel_launch(void* const* d_in, const int* in_sizes, int n_in,
                              void* d_out, int out_size, void* d_ws, size_t ws_size,
                              hipStream_t stream) {
    const float* x  = (const float*)d_in[0];
    const int*   ei = (const int*)d_in[1];
    const float* W1 = (const float*)d_in[2];
    const float* b1 = (const float*)d_in[3];
    const float* W2 = (const float*)d_in[4];
    const float* b2 = (const float*)d_in[5];
    float* out = (float*)d_out;

    const int E = in_sizes[1] / 2;
    const int H1 = in_sizes[3];                 // 128
    const int K1 = in_sizes[2] / H1;            // 256
    const int N = in_sizes[0] / K1;             // 100000
    const int H2 = in_sizes[4] / H1;            // 64
    const int* src = ei;
    const int* dst = ei + E;
    const int NB = (N + 255) >> 8;

    char* ws = (char*)d_ws;
    ushort*   w1th   = (ushort*)(ws + OFF_W1TH);
    ushort*   w1tl   = (ushort*)(ws + OFF_W1TL);
    ushort*   w2th   = (ushort*)(ws + OFF_W2TH);
    ushort*   w2tl   = (ushort*)(ws + OFF_W2TL);
    int*      bcnt   = (int*)(ws + OFF_BCNT);
    int*      bbase  = (int*)(ws + OFF_BBASE);
    int*      bcur   = (int*)(ws + OFF_BCUR);
    int*      rowptr = (int*)(ws + OFF_ROWPTR);
    float*    dinv   = (float*)(ws + OFF_DINV);
    int*      colarr = (int*)(ws + OFF_COL);
    int2*     ebuf   = (int2*)(ws + OFF_EBUF);
    _Float16* h1g    = (_Float16*)(ws + OFF_H1G);
    float*    h1out  = (float*)(ws + OFF_H1OUT);
    _Float16* h2g    = (_Float16*)(ws + OFF_H1G);   // reuse

    hipMemsetAsync(bcnt, 0, 512 * sizeof(int), stream);
    bincount<<<256, 256, 0, stream>>>(dst, bcnt, E);
    bscan<<<1, 512, 0, stream>>>(bcnt, bbase, bcur, rowptr, NB, N, E);
    binscatter<<<(E + CHUNK - 1) / CHUNK, 256, 0, stream>>>(src, dst, bcur, ebuf, E);
    buildcsr<<<NB, 256, 0, stream>>>(ebuf, bbase, bcnt, rowptr, colarr, dinv, N);

    split_wt<<<(K1 * H1 + 255) / 256, 256, 0, stream>>>(W1, w1th, w1tl, K1, H1);
    split_wt<<<(H1 * H2 + 255) / 256, 256, 0, stream>>>(W2, w2th, w2tl, H1, H2);

    // layer 1
    gemm_mfma<128, 256><<<(N + 127) / 128, 256, 0, stream>>>(x, w1th, w1tl, dinv, h1g, N);
    agg_f2h<<<(N + 3) / 4, 256, 0, stream>>>((const __half2*)h1g, rowptr, colarr, dinv, b1,
                                             (float2*)h1out, N);

    // layer 2
    gemm_mfma<64, 128><<<(N + 127) / 128, 256, 0, stream>>>(h1out, w2th, w2tl, dinv, h2g, N);
    agg_f1h<<<(N + 3) / 4, 256, 0, stream>>>(h2g, rowptr, colarr, dinv, b2, out, N);
}